// Round 9
// baseline (380.736 us; speedup 1.0000x reference)
//
#include <hip/hip_runtime.h>

#define NSEQ    2000
#define CHUNK   200
#define NCHUNK  (NSEQ / CHUNK)     // 10 producer blocks
#define GATES   40
#define HID     10
#define XSTRIDE 2016               // xg row stride (floats); 2000+12 prefetch < 2016
#define MAGIC   0x1234ABCDu

__device__ __forceinline__ float rl(float v, int l) {
    return __uint_as_float(__builtin_amdgcn_readlane(__float_as_uint(v), l));
}
template <int CTRL>
__device__ __forceinline__ float qp(float v) {
#if __has_builtin(__builtin_amdgcn_mov_dpp)
    return __int_as_float(
        __builtin_amdgcn_mov_dpp(__float_as_int(v), CTRL, 0xF, 0xF, false));
#else
    return __int_as_float(__builtin_amdgcn_update_dpp(
        __float_as_int(v), __float_as_int(v), CTRL, 0xF, 0xF, false));
#endif
}

// Eigen-style rational tanh: tanh(x) ~= x*P(x^2)/Q(x^2), clamp +-7.90531.
// ONE trans op (rcp) on the dependency chain vs two (exp2->rcp) for the
// exp-based form; P/Q Horner chains overlap. Max err <1e-6 in-range.
__device__ __forceinline__ float tanh_rat(float x) {
    x = fminf(fmaxf(x, -7.90531110763549805f), 7.90531110763549805f);
    const float x2 = x * x;
    float p = 2.00018790482477e-13f;
    p = fmaf(x2, p, -8.60467152213735e-11f);   // skip alpha_13 (negligible in-range)
    p = fmaf(x2, p, 5.12229709037114e-08f);
    p = fmaf(x2, p, 1.48572235717979e-05f);
    p = fmaf(x2, p, 6.37261928875436e-04f);
    p = fmaf(x2, p, 4.89352455891786e-03f);
    p = x * p;
    float q = 1.19825839466702e-06f;
    q = fmaf(x2, q, 1.18534705686654e-04f);
    q = fmaf(x2, q, 2.26843463243900e-03f);
    q = fmaf(x2, q, 4.89352518554385e-03f);
    return p * __builtin_amdgcn_rcpf(q);
}

extern "C" __global__ void __launch_bounds__(256)
msembed_coop(const float* __restrict__ x,
             const float* __restrict__ Wmz1, const float* __restrict__ bmz1,
             const float* __restrict__ Wmz2, const float* __restrict__ bmz2,
             const float* __restrict__ Win1, const float* __restrict__ bin1,
             const float* __restrict__ Win2, const float* __restrict__ bin2,
             const float* __restrict__ Wih,  const float* __restrict__ Whh,
             const float* __restrict__ bih,  const float* __restrict__ bhh,
             float* __restrict__ out, float* __restrict__ ws)
{
    float*    xg    = ws;                                  // 40*2016 floats
    unsigned* flags = (unsigned*)(ws + GATES * XSTRIDE);   // NCHUNK flags
    float*    dmy   = ws + GATES * XSTRIDE + 64;           // scratch for dead lanes

    const int tid = threadIdx.x;

    if (blockIdx.x < NCHUNK) {
        // ================= producer block: 200 rows, 1 row/thread =================
        // Full unroll keeps the ~2.3K weight loads batched (R5: rolling them = 5x).
        const int b = blockIdx.x;
        const int r = b * CHUNK + tid;
        if (tid < CHUNK) {
            const float u = x[2 * r];
            const float w = x[2 * r + 1];
            float tr[32];
            {
                float a[32];
#pragma unroll
                for (int i = 0; i < 32; i++) a[i] = fmaxf(fmaf(Wmz1[i], u, bmz1[i]), 0.f);
#pragma unroll
                for (int o = 0; o < 16; o++) {
                    float acc = bmz2[o];
#pragma unroll
                    for (int k = 0; k < 32; k++) acc = fmaf(Wmz2[o * 32 + k], a[k], acc);
                    tr[o] = fmaxf(acc, 0.f);
                }
#pragma unroll
                for (int i = 0; i < 32; i++) a[i] = fmaxf(fmaf(Win1[i], w, bin1[i]), 0.f);
#pragma unroll
                for (int o = 0; o < 16; o++) {
                    float acc = bin2[o];
#pragma unroll
                    for (int k = 0; k < 32; k++) acc = fmaf(Win2[o * 32 + k], a[k], acc);
                    tr[16 + o] = fmaxf(acc, 0.f);
                }
            }
#pragma unroll
            for (int g = 0; g < GATES; g++) {
                float acc = bih[g] + bhh[g];
#pragma unroll
                for (int k = 0; k < 32; k++) acc = fmaf(Wih[g * 32 + k], tr[k], acc);
                // sigma(a) = 0.5 + 0.5*tanh(a/2): fold the /2 into the i/f/o rows
                const float sc = (g >= 20 && g < 30) ? 1.0f : 0.5f;
                xg[g * XSTRIDE + r] = acc * sc;            // coalesced in r
            }
        }
        __syncthreads();
        if (tid == 0) {
            __threadfence();                               // publish block's stores
            __hip_atomic_store(&flags[b], MAGIC, __ATOMIC_RELEASE,
                               __HIP_MEMORY_SCOPE_AGENT);
        }
        return;
    }

    // ================= recurrence block: one wave, alone on its CU =================
    if (tid >= 64) return;

    // wait ONCE for all producers (~5 us), then run the 2000-step loop clean
    for (int b = 0; b < NCHUNK; b++)
        while (__hip_atomic_load(&flags[b], __ATOMIC_ACQUIRE,
                                 __HIP_MEMORY_SCOPE_AGENT) != MAGIC) {}

    const int lane = tid;
    const int tpe  = lane & 3;          // 0=i 1=f 2=g 3=o
    int j = lane >> 2;
    if (j > HID - 1) j = HID - 1;       // lanes 40-63 mirror unit 9
    const int grow = tpe * 10 + j;
    const bool valid = (tpe == 0) && (lane < 40);

    // whh pre-scaled: /2 for sigmoid rows (half-argument identity), 1 for g rows
    const float wsc = (tpe == 2) ? 1.0f : 0.5f;
    float whh[HID];
#pragma unroll
    for (int k = 0; k < HID; k++) whh[k] = Whh[grow * HID + k] * wsc;

    // sv = pp*tanh_rat(y) + qq:  i/f/o: 0.5*th+0.5 = sigmoid; g: tanh
    const float pp = (tpe == 2) ? 1.0f : 0.5f;
    const float qq = (tpe == 2) ? 0.0f : 0.5f;

    float h = 0.f, c = 0.f;             // real-domain cell (valid lanes t=0,2)
    const float* rowp = xg + grow * XSTRIDE;
    float* op = valid ? (out + j) : (dmy + lane);
    const int opinc = valid ? 4 * HID : 0;

    float4 cur = *reinterpret_cast<const float4*>(rowp);
    float4 nxt = *reinterpret_cast<const float4*>(rowp + 4);
    float4 nx2 = *reinterpret_cast<const float4*>(rowp + 8);

#pragma unroll 1
    for (int s4 = 0; s4 < NSEQ; s4 += 4) {
        const float4 use = cur;
        cur = nxt;
        nxt = nx2;
        nx2 = *reinterpret_cast<const float4*>(rowp + s4 + 12);  // 3-deep prefetch
        const float xs[4] = {use.x, use.y, use.z, use.w};
#pragma unroll
        for (int t = 0; t < 4; t++) {
            float hs[HID];
#pragma unroll
            for (int k = 0; k < HID; k++) hs[k] = rl(h, 4 * k);
            // consume hs in readlane order: chains start at hs[0]/hs[1]
            float a0 = fmaf(hs[0], whh[0], xs[t]);
            float a1 = hs[1] * whh[1];
#pragma unroll
            for (int k = 1; k < 5; k++) {
                a0 = fmaf(hs[2 * k],     whh[2 * k],     a0);
                a1 = fmaf(hs[2 * k + 1], whh[2 * k + 1], a1);
            }
            const float g  = a0 + a1;              // pre-scaled gate argument
            const float sv = fmaf(pp, tanh_rat(g), qq);
            // 3 DPP: pair-swap (i<->g partners), bcast f, bcast o
            const float sw = qp<0x4E>(sv);
            const float sf = qp<0x55>(sv);
            const float so = qp<0xFF>(sv);
            const float pr = sv * sw;              // lanes t=0,2: sig_i*tanh_g
            c = fmaf(sf, c, pr);
            h = so * tanh_rat(c);
            op[t * HID] = h;                       // 10 real lanes -> out
        }
        op += opinc;
    }
}

extern "C" void kernel_launch(void* const* d_in, const int* in_sizes, int n_in,
                              void* d_out, int out_size, void* d_ws, size_t ws_size,
                              hipStream_t stream)
{
    const float* x    = (const float*)d_in[0];
    const float* Wmz1 = (const float*)d_in[1];
    const float* bmz1 = (const float*)d_in[2];
    const float* Wmz2 = (const float*)d_in[3];
    const float* bmz2 = (const float*)d_in[4];
    const float* Win1 = (const float*)d_in[5];
    const float* bin1 = (const float*)d_in[6];
    const float* Win2 = (const float*)d_in[7];
    const float* bin2 = (const float*)d_in[8];
    const float* Wih  = (const float*)d_in[9];
    const float* Whh  = (const float*)d_in[10];
    const float* bih  = (const float*)d_in[11];
    const float* bhh  = (const float*)d_in[12];
    float* out = (float*)d_out;

    hipLaunchKernelGGL(msembed_coop, dim3(NCHUNK + 1), dim3(256), 0, stream,
                       x, Wmz1, bmz1, Wmz2, bmz2, Win1, bin1, Win2, bin2,
                       Wih, Whh, bih, bhh, out, (float*)d_ws);
}

// Round 10
// 286.727 us; speedup vs baseline: 1.3279x; 1.3279x over previous
//
#include <hip/hip_runtime.h>

#define NSEQ    2000
#define CHUNK   200
#define NCHUNK  (NSEQ / CHUNK)     // 10 producer blocks
#define GATES   40
#define HID     10
#define XSTRIDE 2016               // xg row stride (floats); 2000+12 prefetch < 2016
#define LOG2E   1.4426950408889634f
#define MAGIC   0x1234ABCDu

__device__ __forceinline__ float rl(float v, int l) {
    return __uint_as_float(__builtin_amdgcn_readlane(__float_as_uint(v), l));
}
template <int CTRL>
__device__ __forceinline__ float qp(float v) {
#if __has_builtin(__builtin_amdgcn_mov_dpp)
    return __int_as_float(
        __builtin_amdgcn_mov_dpp(__float_as_int(v), CTRL, 0xF, 0xF, false));
#else
    return __int_as_float(__builtin_amdgcn_update_dpp(
        __float_as_int(v), __float_as_int(v), CTRL, 0xF, 0xF, false));
#endif
}

extern "C" __global__ void __launch_bounds__(256)
msembed_coop(const float* __restrict__ x,
             const float* __restrict__ Wmz1, const float* __restrict__ bmz1,
             const float* __restrict__ Wmz2, const float* __restrict__ bmz2,
             const float* __restrict__ Win1, const float* __restrict__ bin1,
             const float* __restrict__ Win2, const float* __restrict__ bin2,
             const float* __restrict__ Wih,  const float* __restrict__ Whh,
             const float* __restrict__ bih,  const float* __restrict__ bhh,
             float* __restrict__ out, float* __restrict__ ws)
{
    float*    xg    = ws;                                  // 40*2016 floats
    unsigned* flags = (unsigned*)(ws + GATES * XSTRIDE);   // NCHUNK flags

    const int tid = threadIdx.x;

    if (blockIdx.x < NCHUNK) {
        // ================= producer block: 200 rows, 1 row/thread =================
        // Full unroll keeps the ~2.3K weight loads batched (R5: rolling them = 5x).
        const int b = blockIdx.x;
        const int r = b * CHUNK + tid;
        if (tid < CHUNK) {
            const float u = x[2 * r];
            const float w = x[2 * r + 1];
            float tr[32];
            {
                float a[32];
#pragma unroll
                for (int i = 0; i < 32; i++) a[i] = fmaxf(fmaf(Wmz1[i], u, bmz1[i]), 0.f);
#pragma unroll
                for (int o = 0; o < 16; o++) {
                    float acc = bmz2[o];
#pragma unroll
                    for (int k = 0; k < 32; k++) acc = fmaf(Wmz2[o * 32 + k], a[k], acc);
                    tr[o] = fmaxf(acc, 0.f);
                }
#pragma unroll
                for (int i = 0; i < 32; i++) a[i] = fmaxf(fmaf(Win1[i], w, bin1[i]), 0.f);
#pragma unroll
                for (int o = 0; o < 16; o++) {
                    float acc = bin2[o];
#pragma unroll
                    for (int k = 0; k < 32; k++) acc = fmaf(Win2[o * 32 + k], a[k], acc);
                    tr[16 + o] = fmaxf(acc, 0.f);
                }
            }
#pragma unroll
            for (int g = 0; g < GATES; g++) {
                float acc = bih[g] + bhh[g];
#pragma unroll
                for (int k = 0; k < 32; k++) acc = fmaf(Wih[g * 32 + k], tr[k], acc);
                // pre-scale by m*log2e: g-rows +2log2e, i/f/o rows -log2e
                const float sc = (g >= 20 && g < 30) ? (2.f * LOG2E) : (-LOG2E);
                xg[g * XSTRIDE + r] = acc * sc;            // coalesced in r
            }
        }
        __syncthreads();
        if (tid == 0) {
            __threadfence();                               // publish block's stores
            __hip_atomic_store(&flags[b], MAGIC, __ATOMIC_RELEASE,
                               __HIP_MEMORY_SCOPE_AGENT);
        }
        return;
    }

    // ================= recurrence block =================
    // h history accumulates in LDS (no vmem stores in the hot loop); all 256
    // threads bulk-copy to global at the end.
    __shared__ __align__(16) float s_h[NSEQ * HID];        // 80,000 B

    if (tid < 64) {
        // wait ONCE for all producers (~5 us), then run 2000 steps clean
        for (int b = 0; b < NCHUNK; b++)
            while (__hip_atomic_load(&flags[b], __ATOMIC_ACQUIRE,
                                     __HIP_MEMORY_SCOPE_AGENT) != MAGIC) {}

        const int lane = tid;
        const int tpe  = lane & 3;          // 0=i 1=f 2=g 3=o
        int j = lane >> 2;
        if (j > HID - 1) j = HID - 1;       // lanes 40-63 mirror unit 9
        const int grow = tpe * 10 + j;

        const float wsc = (tpe == 2) ? (2.f * LOG2E) : (-LOG2E);
        float whh[HID];
#pragma unroll
        for (int k = 0; k < HID; k++) whh[k] = Whh[grow * HID + k] * wsc;

        // sv = pp*rcp(1+exp2(dot)) + qq:  i: 2log2e*sigmoid, f/o: sigmoid, g: tanh
        const float pp = (tpe == 0) ? (2.f * LOG2E) : ((tpe == 2) ? -2.f : 1.f);
        const float qq = (tpe == 2) ? 1.f : 0.f;

        float h = 0.f, c2 = 0.f;            // c2 = 2log2e*c (valid lanes t=0,2)
        const float* rowp = xg + grow * XSTRIDE;

        // lane (4j+t) owns LDS slot t*10+j within each 40-float step-group;
        // lanes 40-63 duplicate a real lane's slot with an identical value.
        float* shp = s_h + (tpe * 10 + j);

        float4 cur = *reinterpret_cast<const float4*>(rowp);
        float4 nxt = *reinterpret_cast<const float4*>(rowp + 4);
        float4 nx2 = *reinterpret_cast<const float4*>(rowp + 8);

#pragma unroll 1
        for (int s4 = 0; s4 < NSEQ; s4 += 4) {
            const float4 use = cur;
            cur = nxt;
            nxt = nx2;
            nx2 = *reinterpret_cast<const float4*>(rowp + s4 + 12); // 3-deep prefetch
            const float xs[4] = {use.x, use.y, use.z, use.w};
            float ha[4];
#pragma unroll
            for (int t = 0; t < 4; t++) {
                float hs[HID];
#pragma unroll
                for (int k = 0; k < HID; k++) hs[k] = rl(h, 4 * k);
                // consume hs in readlane order: chains start at hs[0]/hs[1]
                float a0 = fmaf(hs[0], whh[0], xs[t]);
                float a1 = hs[1] * whh[1];
#pragma unroll
                for (int k = 1; k < 5; k++) {
                    a0 = fmaf(hs[2 * k],     whh[2 * k],     a0);
                    a1 = fmaf(hs[2 * k + 1], whh[2 * k + 1], a1);
                }
                const float g  = a0 + a1;
                const float sv = fmaf(
                    pp, __builtin_amdgcn_rcpf(1.f + __builtin_amdgcn_exp2f(g)), qq);
                // 3 DPP: pair-swap (i<->g partners), bcast f, bcast o
                const float sw = qp<0x4E>(sv);
                const float sf = qp<0x55>(sv);
                const float so = qp<0xFF>(sv);
                const float pr = sv * sw;    // lanes t=0,2: i2*tanh_g
                c2 = fmaf(sf, c2, pr);
                const float th = fmaf(
                    -2.f, __builtin_amdgcn_rcpf(1.f + __builtin_amdgcn_exp2f(c2)), 1.f);
                h = so * th;
                ha[t] = qp<0x00>(h);         // valid h (quad-lane 0) in ALL lanes
            }
            // one LDS write per 4 steps: lane picks its step by type
            const float hv = (tpe == 0) ? ha[0] : (tpe == 1) ? ha[1]
                           : (tpe == 2) ? ha[2] : ha[3];
            *shp = hv;
            shp += 4 * HID;
        }
    }
    __syncthreads();
    // bulk copy LDS -> global, all 256 threads, coalesced float4
    float4*       o4 = reinterpret_cast<float4*>(out);
    const float4* s4p = reinterpret_cast<const float4*>(s_h);
    for (int i = tid; i < NSEQ * HID / 4; i += 256) o4[i] = s4p[i];
}

extern "C" void kernel_launch(void* const* d_in, const int* in_sizes, int n_in,
                              void* d_out, int out_size, void* d_ws, size_t ws_size,
                              hipStream_t stream)
{
    const float* x    = (const float*)d_in[0];
    const float* Wmz1 = (const float*)d_in[1];
    const float* bmz1 = (const float*)d_in[2];
    const float* Wmz2 = (const float*)d_in[3];
    const float* bmz2 = (const float*)d_in[4];
    const float* Win1 = (const float*)d_in[5];
    const float* bin1 = (const float*)d_in[6];
    const float* Win2 = (const float*)d_in[7];
    const float* bin2 = (const float*)d_in[8];
    const float* Wih  = (const float*)d_in[9];
    const float* Whh  = (const float*)d_in[10];
    const float* bih  = (const float*)d_in[11];
    const float* bhh  = (const float*)d_in[12];
    float* out = (float*)d_out;

    hipLaunchKernelGGL(msembed_coop, dim3(NCHUNK + 1), dim3(256), 0, stream,
                       x, Wmz1, bmz1, Wmz2, bmz2, Win1, bin1, Win2, bin2,
                       Wih, Whh, bih, bhh, out, (float*)d_ws);
}